// Round 5
// baseline (228.001 us; speedup 1.0000x reference)
//
#include <hip/hip_runtime.h>
#include <hip/hip_bf16.h>
#include <math.h>

#define N_NODES 10000
#define E_EDGES 320000
#define F_IN    384
#define H1      256
#define H2      128
#define A1      64

typedef __attribute__((ext_vector_type(8))) short bf16x8;
typedef __attribute__((ext_vector_type(4))) float f32x4;

static __device__ inline unsigned short f2bf(float f) {
    unsigned u = __float_as_uint(f);
    unsigned r = (u + 0x7fffu + ((u >> 16) & 1u)) >> 16;   // RNE
    return (unsigned short)r;
}

static __device__ inline unsigned pk2bf(float a, float b) {
    __hip_bfloat162 h2 = __float22bfloat162_rn(make_float2(a, b));
    return *reinterpret_cast<unsigned*>(&h2);   // v_cvt_pk_bf16_f32 on gfx950
}

static __device__ inline float bflo(unsigned v) { return __uint_as_float(v << 16); }
static __device__ inline float bfhi(unsigned v) { return __uint_as_float(v & 0xffff0000u); }

// ---------- fused: weight fp32->bf16 converts + degree count (independent work, one launch)
__global__ void k_convdeg(const float* __restrict__ W1, const float* __restrict__ W2,
                          const float* __restrict__ Wa1,
                          unsigned short* __restrict__ w1b, unsigned short* __restrict__ w2b,
                          unsigned short* __restrict__ wa1b,
                          const int* __restrict__ tgt, int* __restrict__ deg) {
    const int n1 = H1 * F_IN / 4;   // 24576
    const int n2 = H2 * H1 / 4;     // 8192
    const int n3 = A1 * H2 / 4;     // 2048
    const int nc = n1 + n2 + n3;    // 34816
    int i = blockIdx.x * blockDim.x + threadIdx.x;
    if (i < nc) {
        const float4* src;
        ushort4* dst;
        int j;
        if (i < n1)           { src = (const float4*)W1;  dst = (ushort4*)w1b;  j = i; }
        else if (i < n1 + n2) { src = (const float4*)W2;  dst = (ushort4*)w2b;  j = i - n1; }
        else                  { src = (const float4*)Wa1; dst = (ushort4*)wa1b; j = i - n1 - n2; }
        float4 v = src[j];
        ushort4 o;
        o.x = f2bf(v.x); o.y = f2bf(v.y); o.z = f2bf(v.z); o.w = f2bf(v.w);
        dst[j] = o;
    } else {
        int e = i - nc;
        if (e < E_EDGES) atomicAdd(&deg[tgt[e]], 1);
    }
}

// ---------- exclusive scan over deg (single block, 1024 threads, 10 elems/thread)
__global__ __launch_bounds__(1024) void k_scan(const int* __restrict__ deg, int* __restrict__ off,
                                               int* __restrict__ cursor, float* __restrict__ inv) {
    const int CH = 10;
    int tid = threadIdx.x;
    int base = tid * CH;
    int sum = 0;
    int local[CH];
    #pragma unroll
    for (int i = 0; i < CH; i++) {
        int idx = base + i;
        int v = (idx < N_NODES) ? deg[idx] : 0;
        local[i] = sum;
        sum += v;
    }
    __shared__ int sd[1024];
    sd[tid] = sum;
    __syncthreads();
    for (int d = 1; d < 1024; d <<= 1) {
        int v = (tid >= d) ? sd[tid - d] : 0;
        __syncthreads();
        sd[tid] += v;
        __syncthreads();
    }
    int excl = sd[tid] - sum;
    #pragma unroll
    for (int i = 0; i < CH; i++) {
        int idx = base + i;
        if (idx < N_NODES) {
            int o = local[i] + excl;
            off[idx] = o;
            cursor[idx] = o;
            inv[idx] = 1.0f / (float)(deg[idx] + 1);
        }
    }
    if (tid == 1023) off[N_NODES] = sd[1023];
}

// ---------- CSR bin fill
__global__ void k_fill(const int* __restrict__ src, const int* __restrict__ tgt,
                       int* __restrict__ cursor, int* __restrict__ csr) {
    int e = blockIdx.x * blockDim.x + threadIdx.x;
    if (e < E_EDGES) {
        int t = tgt[e];
        int p = atomicAdd(&cursor[t], 1);
        csr[p] = src[e];
    }
}

// ---------- fc1 MFMA: h = relu(x @ W1^T + b1), fp32 x converted inline, bf16 out in 2 planes
// block = 256 = 4 waves; 32 rows/block (2 row-tiles per wave); wave w -> cols [w*64, w*64+64)
__global__ __launch_bounds__(256) void k_fc1(const float* __restrict__ x,
                                             const unsigned short* __restrict__ w1b,
                                             const float* __restrict__ b1,
                                             unsigned short* __restrict__ h /* 2 planes of N*128 */) {
    int wave = threadIdx.x >> 6;
    int lane = threadIdx.x & 63;
    int m0 = blockIdx.x * 32;
    int nbase = wave * 64;
    int ml = lane & 15, quad = lane >> 4;
    int ra0 = m0 + ml;
    int ra1 = m0 + 16 + ml; if (ra1 > N_NODES - 1) ra1 = N_NODES - 1;   // clamp OOB reads
    const float* Ar0 = x + (size_t)ra0 * F_IN + quad * 8;
    const float* Ar1 = x + (size_t)ra1 * F_IN + quad * 8;
    const bf16x8* Brow[4];
    #pragma unroll
    for (int j = 0; j < 4; j++)
        Brow[j] = (const bf16x8*)(w1b + (size_t)(nbase + j * 16 + ml) * F_IN + quad * 8);
    f32x4 acc0[4] = {{0,0,0,0},{0,0,0,0},{0,0,0,0},{0,0,0,0}};
    f32x4 acc1[4] = {{0,0,0,0},{0,0,0,0},{0,0,0,0},{0,0,0,0}};
    for (int kk = 0; kk < F_IN / 32; kk++) {
        float4 f0 = *(const float4*)(Ar0 + kk * 32);
        float4 f1 = *(const float4*)(Ar0 + kk * 32 + 4);
        float4 g0 = *(const float4*)(Ar1 + kk * 32);
        float4 g1 = *(const float4*)(Ar1 + kk * 32 + 4);
        bf16x8 a0, a1;
        ((unsigned*)&a0)[0] = pk2bf(f0.x, f0.y);
        ((unsigned*)&a0)[1] = pk2bf(f0.z, f0.w);
        ((unsigned*)&a0)[2] = pk2bf(f1.x, f1.y);
        ((unsigned*)&a0)[3] = pk2bf(f1.z, f1.w);
        ((unsigned*)&a1)[0] = pk2bf(g0.x, g0.y);
        ((unsigned*)&a1)[1] = pk2bf(g0.z, g0.w);
        ((unsigned*)&a1)[2] = pk2bf(g1.x, g1.y);
        ((unsigned*)&a1)[3] = pk2bf(g1.z, g1.w);
        #pragma unroll
        for (int j = 0; j < 4; j++) {
            bf16x8 b = Brow[j][kk * 4];
            acc0[j] = __builtin_amdgcn_mfma_f32_16x16x32_bf16(a0, b, acc0[j], 0, 0, 0);
            acc1[j] = __builtin_amdgcn_mfma_f32_16x16x32_bf16(a1, b, acc1[j], 0, 0, 0);
        }
    }
    #pragma unroll
    for (int j = 0; j < 4; j++) {
        int col = nbase + j * 16 + ml;
        int plane = col >> 7, d = col & 127;
        unsigned short* hp = h + (size_t)plane * N_NODES * 128;
        float bb = b1[col];
        #pragma unroll
        for (int r = 0; r < 4; r++) {
            int row0 = m0 + quad * 4 + r;
            int row1 = row0 + 16;
            float v0 = acc0[j][r] + bb;
            v0 = v0 > 0.f ? v0 : 0.f;
            hp[(size_t)row0 * 128 + d] = f2bf(v0);
            if (row1 < N_NODES) {
                float v1 = acc1[j][r] + bb;
                v1 = v1 > 0.f ? v1 : 0.f;
                hp[(size_t)row1 * 128 + d] = f2bf(v1);
            }
        }
    }
}

// ---------- aggregation on one 128-dim plane (2.56 MB table -> L2-resident per XCD)
// 4 nodes per 256-thread block; lane = 1 uint (2 bf16); wave reads 256 B/edge
__global__ __launch_bounds__(256) void k_aggp(const unsigned short* __restrict__ hin_p,
                                              unsigned short* __restrict__ hout_p,
                                              const int* __restrict__ off,
                                              const int* __restrict__ csr,
                                              const float* __restrict__ inv) {
    int t = blockIdx.x * 4 + (threadIdx.x >> 6);
    int tid = threadIdx.x & 63;
    int s0 = off[t], s1 = off[t + 1];
    const unsigned* base = (const unsigned*)hin_p;   // row stride 64 uints
    float a0 = 0.f, a1 = 0.f;
    int e = s0;
    for (; e + 4 <= s1; e += 4) {
        int sA = csr[e], sB = csr[e + 1], sC = csr[e + 2], sD = csr[e + 3];
        unsigned vA = base[(size_t)sA * 64 + tid];
        unsigned vB = base[(size_t)sB * 64 + tid];
        unsigned vC = base[(size_t)sC * 64 + tid];
        unsigned vD = base[(size_t)sD * 64 + tid];
        a0 += bflo(vA); a1 += bfhi(vA);
        a0 += bflo(vB); a1 += bfhi(vB);
        a0 += bflo(vC); a1 += bfhi(vC);
        a0 += bflo(vD); a1 += bfhi(vD);
    }
    for (; e < s1; e++) {
        int s = csr[e];
        unsigned v = base[(size_t)s * 64 + tid];
        a0 += bflo(v); a1 += bfhi(v);
    }
    unsigned sv = base[(size_t)t * 64 + tid];
    float iv = 0.3f * inv[t];
    float r0 = 0.7f * bflo(sv) + iv * a0;
    float r1 = 0.7f * bfhi(sv) + iv * a1;
    unsigned ov = pk2bf(r0, r1);
    // nontemporal: don't evict the gather table with the output stream
    __builtin_nontemporal_store(ov, (unsigned*)hout_p + (size_t)t * 64 + tid);
}

// ---------- fc2 + attention fused:
// out = relu(h @ W2^T + b2) -> d_out; att = sigmoid(relu(out @ Wa1^T + ba1) @ Wa2^T + ba2)
// block = 128 = 2 waves; 32 rows/block; out tile staged bf16 in LDS for the att GEMM
#define SLDS 136   // padded row stride (ushorts): 272 B = 17*16 B, 2-way max bank aliasing
__global__ __launch_bounds__(128) void k_fc2att(const unsigned short* __restrict__ h /* 2 planes */,
                                                const unsigned short* __restrict__ w2b,
                                                const float* __restrict__ b2,
                                                const unsigned short* __restrict__ wa1b,
                                                const float* __restrict__ ba1,
                                                const float* __restrict__ Wa2,
                                                const float* __restrict__ ba2,
                                                float* __restrict__ out,
                                                float* __restrict__ att) {
    __shared__ unsigned short sout[32 * SLDS];
    int wave = threadIdx.x >> 6;
    int lane = threadIdx.x & 63;
    int m0 = blockIdx.x * 32;
    int nbase = wave * 64;
    int ml = lane & 15, quad = lane >> 4;
    int ra0 = m0 + ml;
    int ra1 = m0 + 16 + ml; if (ra1 > N_NODES + 14) ra1 = N_NODES + 14;  // stays inside ws (h1 follows h0)
    const bf16x8* Brow[4];
    #pragma unroll
    for (int j = 0; j < 4; j++)
        Brow[j] = (const bf16x8*)(w2b + (size_t)(nbase + j * 16 + ml) * H1 + quad * 8);
    f32x4 acc0[4] = {{0,0,0,0},{0,0,0,0},{0,0,0,0},{0,0,0,0}};
    f32x4 acc1[4] = {{0,0,0,0},{0,0,0,0},{0,0,0,0},{0,0,0,0}};
    #pragma unroll
    for (int kk = 0; kk < H1 / 32; kk++) {
        const unsigned short* pb = h + (size_t)(kk >> 2) * N_NODES * 128;
        int d = (kk & 3) * 32 + quad * 8;
        bf16x8 a0 = *(const bf16x8*)(pb + (size_t)ra0 * 128 + d);
        bf16x8 a1 = *(const bf16x8*)(pb + (size_t)ra1 * 128 + d);
        #pragma unroll
        for (int j = 0; j < 4; j++) {
            bf16x8 b = Brow[j][kk * 4];
            acc0[j] = __builtin_amdgcn_mfma_f32_16x16x32_bf16(a0, b, acc0[j], 0, 0, 0);
            acc1[j] = __builtin_amdgcn_mfma_f32_16x16x32_bf16(a1, b, acc1[j], 0, 0, 0);
        }
    }
    #pragma unroll
    for (int j = 0; j < 4; j++) {
        int col = nbase + j * 16 + ml;
        float bb = b2[col];
        #pragma unroll
        for (int r = 0; r < 4; r++) {
            int lr0 = quad * 4 + r;
            int row0 = m0 + lr0;
            int row1 = row0 + 16;
            float v0 = acc0[j][r] + bb;
            v0 = v0 > 0.f ? v0 : 0.f;
            out[(size_t)row0 * H2 + col] = v0;
            sout[lr0 * SLDS + col] = f2bf(v0);
            float v1 = acc1[j][r] + bb;
            v1 = v1 > 0.f ? v1 : 0.f;
            if (row1 < N_NODES) out[(size_t)row1 * H2 + col] = v1;
            sout[(lr0 + 16) * SLDS + col] = f2bf(v1);
        }
    }
    __syncthreads();
    // ---- attention GEMM: wave w -> rows [w*16, w*16+16), N=64, K=128, A from LDS
    int mrow = wave * 16 + ml;
    const unsigned short* Abase = sout + mrow * SLDS + quad * 8;
    const bf16x8* Brow2[4];
    #pragma unroll
    for (int j = 0; j < 4; j++)
        Brow2[j] = (const bf16x8*)(wa1b + (size_t)(j * 16 + ml) * H2 + quad * 8);
    f32x4 acc[4] = {{0,0,0,0},{0,0,0,0},{0,0,0,0},{0,0,0,0}};
    #pragma unroll
    for (int kk = 0; kk < H2 / 32; kk++) {
        bf16x8 a = *(const bf16x8*)(Abase + kk * 32);
        #pragma unroll
        for (int j = 0; j < 4; j++) {
            bf16x8 b = Brow2[j][kk * 4];
            acc[j] = __builtin_amdgcn_mfma_f32_16x16x32_bf16(a, b, acc[j], 0, 0, 0);
        }
    }
    float v0 = 0.f, v1 = 0.f, v2 = 0.f, v3 = 0.f;
    #pragma unroll
    for (int j = 0; j < 4; j++) {
        int col = j * 16 + ml;
        float bb = ba1[col];
        float w2 = Wa2[col];
        float z;
        z = acc[j][0] + bb; v0 += (z > 0.f ? z : 0.f) * w2;
        z = acc[j][1] + bb; v1 += (z > 0.f ? z : 0.f) * w2;
        z = acc[j][2] + bb; v2 += (z > 0.f ? z : 0.f) * w2;
        z = acc[j][3] + bb; v3 += (z > 0.f ? z : 0.f) * w2;
    }
    #pragma unroll
    for (int d = 1; d < 16; d <<= 1) {
        v0 += __shfl_xor(v0, d, 64);
        v1 += __shfl_xor(v1, d, 64);
        v2 += __shfl_xor(v2, d, 64);
        v3 += __shfl_xor(v3, d, 64);
    }
    if (ml < 4) {
        float v = ml == 0 ? v0 : ml == 1 ? v1 : ml == 2 ? v2 : v3;
        v += ba2[0];
        int row = m0 + wave * 16 + quad * 4 + ml;
        if (row < N_NODES) att[row] = 1.f / (1.f + expf(-v));
    }
}

extern "C" void kernel_launch(void* const* d_in, const int* in_sizes, int n_in,
                              void* d_out, int out_size, void* d_ws, size_t ws_size,
                              hipStream_t stream) {
    const float* x   = (const float*)d_in[0];
    const int*   ei  = (const int*)d_in[1];
    const float* W1  = (const float*)d_in[2];
    const float* b1  = (const float*)d_in[3];
    const float* W2  = (const float*)d_in[4];
    const float* b2  = (const float*)d_in[5];
    const float* Wa1 = (const float*)d_in[6];
    const float* ba1 = (const float*)d_in[7];
    const float* Wa2 = (const float*)d_in[8];
    const float* ba2 = (const float*)d_in[9];
    const int* src = ei;
    const int* tgt = ei + E_EDGES;

    float* out_mat = (float*)d_out;                 // N x 128
    float* att     = out_mat + N_NODES * H2;        // N x 1

    // workspace layout
    unsigned short* w1b  = (unsigned short*)d_ws;                // H1*F_IN
    unsigned short* w2b  = w1b + (size_t)H1 * F_IN;              // H2*H1
    unsigned short* wa1b = w2b + (size_t)H2 * H1;                // A1*H2
    unsigned short* h0   = wa1b + (size_t)A1 * H2;               // 2 planes x N*128
    unsigned short* h1   = h0 + (size_t)2 * N_NODES * 128;       // 2 planes x N*128
    float* inv  = (float*)(h1 + (size_t)2 * N_NODES * 128);      // N
    int* deg    = (int*)(inv + N_NODES);                         // N
    int* off    = deg + N_NODES;                                 // N+1
    int* cursor = off + N_NODES + 1;                             // N
    int* csr    = cursor + N_NODES;                              // E

    hipMemsetAsync(deg, 0, N_NODES * sizeof(int), stream);

    // weight converts + degree count (fused)
    {
        const int nc = (H1 * F_IN + H2 * H1 + A1 * H2) / 4;  // 34816
        int total = nc + E_EDGES;
        k_convdeg<<<(total + 255) / 256, 256, 0, stream>>>(W1, W2, Wa1, w1b, w2b, wa1b, tgt, deg);
    }

    k_scan<<<1, 1024, 0, stream>>>(deg, off, cursor, inv);
    k_fill<<<(E_EDGES + 255) / 256, 256, 0, stream>>>(src, tgt, cursor, csr);

    // fc1 (MFMA, inline x convert) -> h0 planes
    k_fc1<<<(N_NODES + 31) / 32, 256, 0, stream>>>(x, w1b, b1, h0);

    // aggregation: per-plane chains (keeps each 2.56 MB table L2-resident)
    const size_t PL = (size_t)N_NODES * 128;
    k_aggp<<<N_NODES / 4, 256, 0, stream>>>(h0,       h1,       off, csr, inv);  // p0 pass1
    k_aggp<<<N_NODES / 4, 256, 0, stream>>>(h1,       h0,       off, csr, inv);  // p0 pass2
    k_aggp<<<N_NODES / 4, 256, 0, stream>>>(h0 + PL,  h1 + PL,  off, csr, inv);  // p1 pass1
    k_aggp<<<N_NODES / 4, 256, 0, stream>>>(h1 + PL,  h0 + PL,  off, csr, inv);  // p1 pass2

    // fc2 + attention (fused) -> out + att
    k_fc2att<<<(N_NODES + 31) / 32, 128, 0, stream>>>(h0, w2b, b2, wa1b, ba1, Wa2, ba2, out_mat, att);
}

// Round 7
// 201.429 us; speedup vs baseline: 1.1319x; 1.1319x over previous
//
#include <hip/hip_runtime.h>
#include <hip/hip_bf16.h>
#include <math.h>

#define N_NODES 10000
#define NP      10016   // padded row count for z buffers (32-row tiles, no store guards)
#define E_EDGES 320000
#define F_IN    384
#define H1      256
#define H2      128
#define ATT1    64

typedef __attribute__((ext_vector_type(8))) short bf16x8;
typedef __attribute__((ext_vector_type(4))) float f32x4;

static __device__ inline unsigned short f2bf(float f) {
    unsigned u = __float_as_uint(f);
    unsigned r = (u + 0x7fffu + ((u >> 16) & 1u)) >> 16;   // RNE
    return (unsigned short)r;
}

static __device__ inline unsigned pk2bf(float a, float b) {
    __hip_bfloat162 h2 = __float22bfloat162_rn(make_float2(a, b));
    return *reinterpret_cast<unsigned*>(&h2);   // v_cvt_pk_bf16_f32
}

static __device__ inline float bflo(unsigned v) { return __uint_as_float(v << 16); }
static __device__ inline float bfhi(unsigned v) { return __uint_as_float(v & 0xffff0000u); }

// ---------- fused: weight fp32->bf16 converts + degree count
__global__ void k_convdeg(const float* __restrict__ W1, const float* __restrict__ W2,
                          const float* __restrict__ Wa1,
                          unsigned short* __restrict__ w1b, unsigned short* __restrict__ w2b,
                          unsigned short* __restrict__ wa1b,
                          const int* __restrict__ tgt, int* __restrict__ deg) {
    const int n1 = H1 * F_IN / 4;   // 24576
    const int n2 = H2 * H1 / 4;     // 8192
    const int n3 = ATT1 * H2 / 4;   // 2048
    const int nc = n1 + n2 + n3;    // 34816
    int i = blockIdx.x * blockDim.x + threadIdx.x;
    if (i < nc) {
        const float4* src;
        ushort4* dst;
        int j;
        if (i < n1)           { src = (const float4*)W1;  dst = (ushort4*)w1b;  j = i; }
        else if (i < n1 + n2) { src = (const float4*)W2;  dst = (ushort4*)w2b;  j = i - n1; }
        else                  { src = (const float4*)Wa1; dst = (ushort4*)wa1b; j = i - n1 - n2; }
        float4 v = src[j];
        ushort4 o;
        o.x = f2bf(v.x); o.y = f2bf(v.y); o.z = f2bf(v.z); o.w = f2bf(v.w);
        dst[j] = o;
    } else {
        int e = i - nc;
        if (e < E_EDGES) atomicAdd(&deg[tgt[e]], 1);
    }
}

// ---------- exclusive scan over deg (single block, 1024 threads)
__global__ __launch_bounds__(1024) void k_scan(const int* __restrict__ deg, int* __restrict__ off,
                                               int* __restrict__ cursor, float* __restrict__ inv) {
    const int CH = 10;
    int tid = threadIdx.x;
    int base = tid * CH;
    int sum = 0;
    int local[CH];
    #pragma unroll
    for (int i = 0; i < CH; i++) {
        int idx = base + i;
        int v = (idx < N_NODES) ? deg[idx] : 0;
        local[i] = sum;
        sum += v;
    }
    __shared__ int sd[1024];
    sd[tid] = sum;
    __syncthreads();
    for (int d = 1; d < 1024; d <<= 1) {
        int v = (tid >= d) ? sd[tid - d] : 0;
        __syncthreads();
        sd[tid] += v;
        __syncthreads();
    }
    int excl = sd[tid] - sum;
    #pragma unroll
    for (int i = 0; i < CH; i++) {
        int idx = base + i;
        if (idx < N_NODES) {
            int o = local[i] + excl;
            off[idx] = o;
            cursor[idx] = o;
            inv[idx] = 1.0f / (float)(deg[idx] + 1);
        }
    }
    if (tid == 1023) off[N_NODES] = sd[1023];
}

// ---------- CSR bin fill
__global__ void k_fill(const int* __restrict__ src, const int* __restrict__ tgt,
                       int* __restrict__ cursor, int* __restrict__ csr) {
    int e = blockIdx.x * blockDim.x + threadIdx.x;
    if (e < E_EDGES) {
        int t = tgt[e];
        int p = atomicAdd(&cursor[t], 1);
        csr[p] = src[e];
    }
}

// ---------- fused fc1+proj: z = relu(x @ W1^T + b1) @ W2^T   (N x 128, bf16, NO bias/relu on z)
// block = 256 = 4 waves; 32 rows/block. Stage1: h-tile (32x256) -> LDS. Stage2: z-tile (32x128).
#define S1 264   // LDS row stride (ushorts) for the 32x256 h tile: 528 B, 2-way bank max
__global__ __launch_bounds__(256) void k_fc12(const float* __restrict__ x,
                                              const unsigned short* __restrict__ w1b,
                                              const float* __restrict__ b1,
                                              const unsigned short* __restrict__ w2b,
                                              unsigned short* __restrict__ z) {
    __shared__ unsigned short sh[32 * S1];
    int wave = threadIdx.x >> 6;
    int lane = threadIdx.x & 63;
    int m0 = blockIdx.x * 32;
    int ml = lane & 15, quad = lane >> 4;
    // ---- stage 1: h = relu(x @ W1^T + b1), inline fp32->bf16 convert of x
    {
        int nbase = wave * 64;
        int ra0 = m0 + ml;
        int ra1 = m0 + 16 + ml; if (ra1 > N_NODES - 1) ra1 = N_NODES - 1;
        const float* Ar0 = x + (size_t)ra0 * F_IN + quad * 8;
        const float* Ar1 = x + (size_t)ra1 * F_IN + quad * 8;
        const bf16x8* Brow[4];
        #pragma unroll
        for (int j = 0; j < 4; j++)
            Brow[j] = (const bf16x8*)(w1b + (size_t)(nbase + j * 16 + ml) * F_IN + quad * 8);
        f32x4 acc0[4] = {{0,0,0,0},{0,0,0,0},{0,0,0,0},{0,0,0,0}};
        f32x4 acc1[4] = {{0,0,0,0},{0,0,0,0},{0,0,0,0},{0,0,0,0}};
        for (int kk = 0; kk < F_IN / 32; kk++) {
            float4 f0 = *(const float4*)(Ar0 + kk * 32);
            float4 f1 = *(const float4*)(Ar0 + kk * 32 + 4);
            float4 g0 = *(const float4*)(Ar1 + kk * 32);
            float4 g1 = *(const float4*)(Ar1 + kk * 32 + 4);
            bf16x8 a0, a1;
            ((unsigned*)&a0)[0] = pk2bf(f0.x, f0.y);
            ((unsigned*)&a0)[1] = pk2bf(f0.z, f0.w);
            ((unsigned*)&a0)[2] = pk2bf(f1.x, f1.y);
            ((unsigned*)&a0)[3] = pk2bf(f1.z, f1.w);
            ((unsigned*)&a1)[0] = pk2bf(g0.x, g0.y);
            ((unsigned*)&a1)[1] = pk2bf(g0.z, g0.w);
            ((unsigned*)&a1)[2] = pk2bf(g1.x, g1.y);
            ((unsigned*)&a1)[3] = pk2bf(g1.z, g1.w);
            #pragma unroll
            for (int j = 0; j < 4; j++) {
                bf16x8 b = Brow[j][kk * 4];
                acc0[j] = __builtin_amdgcn_mfma_f32_16x16x32_bf16(a0, b, acc0[j], 0, 0, 0);
                acc1[j] = __builtin_amdgcn_mfma_f32_16x16x32_bf16(a1, b, acc1[j], 0, 0, 0);
            }
        }
        #pragma unroll
        for (int j = 0; j < 4; j++) {
            int col = nbase + j * 16 + ml;
            float bb = b1[col];
            #pragma unroll
            for (int r = 0; r < 4; r++) {
                int lr = quad * 4 + r;
                float v0 = acc0[j][r] + bb;
                sh[lr * S1 + col] = f2bf(v0 > 0.f ? v0 : 0.f);
                float v1 = acc1[j][r] + bb;
                sh[(lr + 16) * S1 + col] = f2bf(v1 > 0.f ? v1 : 0.f);
            }
        }
    }
    __syncthreads();
    // ---- stage 2: z = h @ W2^T, wave w -> cols [w*32, w*32+32), A from LDS
    {
        int c0 = wave * 32;
        const unsigned short* pA0 = sh + ml * S1 + quad * 8;
        const unsigned short* pA1 = sh + (16 + ml) * S1 + quad * 8;
        const bf16x8* B0 = (const bf16x8*)(w2b + (size_t)(c0 + ml) * H1 + quad * 8);
        const bf16x8* B1 = (const bf16x8*)(w2b + (size_t)(c0 + 16 + ml) * H1 + quad * 8);
        f32x4 za[2][2] = {{{0,0,0,0},{0,0,0,0}},{{0,0,0,0},{0,0,0,0}}};
        #pragma unroll
        for (int kk = 0; kk < H1 / 32; kk++) {
            bf16x8 a0 = *(const bf16x8*)(pA0 + kk * 32);
            bf16x8 a1 = *(const bf16x8*)(pA1 + kk * 32);
            bf16x8 b0 = B0[kk * 4];
            bf16x8 b1 = B1[kk * 4];
            za[0][0] = __builtin_amdgcn_mfma_f32_16x16x32_bf16(a0, b0, za[0][0], 0, 0, 0);
            za[1][0] = __builtin_amdgcn_mfma_f32_16x16x32_bf16(a1, b0, za[1][0], 0, 0, 0);
            za[0][1] = __builtin_amdgcn_mfma_f32_16x16x32_bf16(a0, b1, za[0][1], 0, 0, 0);
            za[1][1] = __builtin_amdgcn_mfma_f32_16x16x32_bf16(a1, b1, za[1][1], 0, 0, 0);
        }
        #pragma unroll
        for (int j2 = 0; j2 < 2; j2++) {
            int col = c0 + j2 * 16 + ml;
            #pragma unroll
            for (int r = 0; r < 4; r++) {
                int row0 = m0 + quad * 4 + r;          // z padded to NP rows: no guard
                z[(size_t)row0 * H2 + col] = f2bf(za[0][j2][r]);
                z[(size_t)(row0 + 16) * H2 + col] = f2bf(za[1][j2][r]);
            }
        }
    }
}

// ---------- aggregation on 128-dim z (256 B rows): zout[t] = 0.7*zin[t] + 0.3*inv[t]*sum zin[nbr]
// 4 nodes per 256-thread block; lane = 1 uint (2 bf16); unroll-4 edge loop
__global__ __launch_bounds__(256) void k_agg(const unsigned short* __restrict__ zin,
                                             unsigned short* __restrict__ zout,
                                             const int* __restrict__ off,
                                             const int* __restrict__ csr,
                                             const float* __restrict__ inv) {
    int t = blockIdx.x * 4 + (threadIdx.x >> 6);
    int tid = threadIdx.x & 63;
    int s0 = off[t], s1 = off[t + 1];
    const unsigned* base = (const unsigned*)zin;   // row stride 64 uints
    float a0 = 0.f, a1 = 0.f;
    int e = s0;
    for (; e + 4 <= s1; e += 4) {
        int sA = csr[e], sB = csr[e + 1], sC = csr[e + 2], sD = csr[e + 3];
        unsigned vA = base[(size_t)sA * 64 + tid];
        unsigned vB = base[(size_t)sB * 64 + tid];
        unsigned vC = base[(size_t)sC * 64 + tid];
        unsigned vD = base[(size_t)sD * 64 + tid];
        a0 += bflo(vA); a1 += bfhi(vA);
        a0 += bflo(vB); a1 += bfhi(vB);
        a0 += bflo(vC); a1 += bfhi(vC);
        a0 += bflo(vD); a1 += bfhi(vD);
    }
    for (; e < s1; e++) {
        int s = csr[e];
        unsigned v = base[(size_t)s * 64 + tid];
        a0 += bflo(v); a1 += bfhi(v);
    }
    unsigned sv = base[(size_t)t * 64 + tid];
    float iv = 0.3f * inv[t];
    float r0 = 0.7f * bflo(sv) + iv * a0;
    float r1 = 0.7f * bfhi(sv) + iv * a1;
    unsigned ov = pk2bf(r0, r1);
    __builtin_nontemporal_store(ov, (unsigned*)zout + (size_t)t * 64 + tid);
}

// ---------- final: out = relu(z_agg + b2); att = sigmoid(relu(out @ Wa1^T + ba1) @ Wa2^T + ba2)
// block = 128 = 2 waves; 32 rows/block; out tile bf16 in LDS for the att GEMM
#define S2 136   // padded LDS row stride (ushorts)
__global__ __launch_bounds__(128) void k_final(const unsigned short* __restrict__ z,
                                               const float* __restrict__ b2,
                                               const unsigned short* __restrict__ wa1b,
                                               const float* __restrict__ ba1,
                                               const float* __restrict__ Wa2,
                                               const float* __restrict__ ba2,
                                               float* __restrict__ out,
                                               float* __restrict__ att) {
    __shared__ unsigned short so[32 * S2];
    int m0 = blockIdx.x * 32;
    int tid = threadIdx.x;
    // ---- elementwise: thread -> row (tid>>2), col segment (tid&3)*32
    {
        int rl = tid >> 2;
        int cs = (tid & 3) * 32;
        int grow = m0 + rl;
        bool wr = grow < N_NODES;
        const unsigned* zr = (const unsigned*)(z + (size_t)(m0 + rl) * H2 + cs);
        #pragma unroll
        for (int i = 0; i < 16; i += 2) {   // 16 uints = 32 bf16
            unsigned v0 = zr[i], v1 = zr[i + 1];
            int c = cs + i * 2;
            float f0 = bflo(v0) + b2[c];     f0 = f0 > 0.f ? f0 : 0.f;
            float f1 = bfhi(v0) + b2[c + 1]; f1 = f1 > 0.f ? f1 : 0.f;
            float f2 = bflo(v1) + b2[c + 2]; f2 = f2 > 0.f ? f2 : 0.f;
            float f3 = bfhi(v1) + b2[c + 3]; f3 = f3 > 0.f ? f3 : 0.f;
            if (wr) *(float4*)(out + (size_t)grow * H2 + c) = make_float4(f0, f1, f2, f3);
            unsigned* sp = (unsigned*)(so + rl * S2 + c);
            sp[0] = pk2bf(f0, f1);
            sp[1] = pk2bf(f2, f3);
        }
    }
    __syncthreads();
    // ---- att GEMM: wave w -> rows [w*16, w*16+16), N=64 cols, K=128, A from LDS
    int wave = tid >> 6;
    int lane = tid & 63;
    int ml = lane & 15, quad = lane >> 4;
    const unsigned short* Abase = so + (wave * 16 + ml) * S2 + quad * 8;
    const bf16x8* Brow[4];
    #pragma unroll
    for (int j = 0; j < 4; j++)
        Brow[j] = (const bf16x8*)(wa1b + (size_t)(j * 16 + ml) * H2 + quad * 8);
    f32x4 acc[4] = {{0,0,0,0},{0,0,0,0},{0,0,0,0},{0,0,0,0}};
    #pragma unroll
    for (int kk = 0; kk < H2 / 32; kk++) {
        bf16x8 a = *(const bf16x8*)(Abase + kk * 32);
        #pragma unroll
        for (int j = 0; j < 4; j++) {
            bf16x8 b = Brow[j][kk * 4];
            acc[j] = __builtin_amdgcn_mfma_f32_16x16x32_bf16(a, b, acc[j], 0, 0, 0);
        }
    }
    float v0 = 0.f, v1 = 0.f, v2 = 0.f, v3 = 0.f;
    #pragma unroll
    for (int j = 0; j < 4; j++) {
        int col = j * 16 + ml;
        float bb = ba1[col];
        float w2 = Wa2[col];
        float zz;
        zz = acc[j][0] + bb; v0 += (zz > 0.f ? zz : 0.f) * w2;
        zz = acc[j][1] + bb; v1 += (zz > 0.f ? zz : 0.f) * w2;
        zz = acc[j][2] + bb; v2 += (zz > 0.f ? zz : 0.f) * w2;
        zz = acc[j][3] + bb; v3 += (zz > 0.f ? zz : 0.f) * w2;
    }
    #pragma unroll
    for (int d = 1; d < 16; d <<= 1) {
        v0 += __shfl_xor(v0, d, 64);
        v1 += __shfl_xor(v1, d, 64);
        v2 += __shfl_xor(v2, d, 64);
        v3 += __shfl_xor(v3, d, 64);
    }
    if (ml < 4) {
        float v = ml == 0 ? v0 : ml == 1 ? v1 : ml == 2 ? v2 : v3;
        v += ba2[0];
        int row = m0 + wave * 16 + quad * 4 + ml;
        if (row < N_NODES) att[row] = 1.f / (1.f + expf(-v));
    }
}

extern "C" void kernel_launch(void* const* d_in, const int* in_sizes, int n_in,
                              void* d_out, int out_size, void* d_ws, size_t ws_size,
                              hipStream_t stream) {
    const float* x   = (const float*)d_in[0];
    const int*   ei  = (const int*)d_in[1];
    const float* W1  = (const float*)d_in[2];
    const float* b1  = (const float*)d_in[3];
    const float* W2  = (const float*)d_in[4];
    const float* b2  = (const float*)d_in[5];
    const float* Wa1 = (const float*)d_in[6];
    const float* ba1 = (const float*)d_in[7];
    const float* Wa2 = (const float*)d_in[8];
    const float* ba2 = (const float*)d_in[9];
    const int* src = ei;
    const int* tgt = ei + E_EDGES;

    float* out_mat = (float*)d_out;                 // N x 128
    float* att     = out_mat + N_NODES * H2;        // N x 1

    // workspace layout
    unsigned short* w1b  = (unsigned short*)d_ws;                // H1*F_IN
    unsigned short* w2b  = w1b + (size_t)H1 * F_IN;              // H2*H1
    unsigned short* wa1b = w2b + (size_t)H2 * H1;                // ATT1*H2
    unsigned short* z0   = wa1b + (size_t)ATT1 * H2;             // NP*128
    unsigned short* z1   = z0 + (size_t)NP * H2;                 // NP*128
    float* inv  = (float*)(z1 + (size_t)NP * H2);                // N
    int* deg    = (int*)(inv + N_NODES);                         // N
    int* off    = deg + N_NODES;                                 // N+1
    int* cursor = off + N_NODES + 1;                             // N
    int* csr    = cursor + N_NODES;                              // E

    hipMemsetAsync(deg, 0, N_NODES * sizeof(int), stream);

    // weight converts + degree count (fused)
    {
        const int nc = (H1 * F_IN + H2 * H1 + ATT1 * H2) / 4;  // 34816
        int total = nc + E_EDGES;
        k_convdeg<<<(total + 255) / 256, 256, 0, stream>>>(W1, W2, Wa1, w1b, w2b, wa1b, tgt, deg);
    }

    k_scan<<<1, 1024, 0, stream>>>(deg, off, cursor, inv);
    k_fill<<<(E_EDGES + 255) / 256, 256, 0, stream>>>(src, tgt, cursor, csr);

    // fused fc1 + projection by W2^T -> z0 (N x 128 bf16, pre-bias/relu)
    k_fc12<<<(N_NODES + 31) / 32, 256, 0, stream>>>(x, w1b, b1, w2b, z0);

    // 2 aggregation passes in the 128-dim projected space (256 B gather rows)
    k_agg<<<N_NODES / 4, 256, 0, stream>>>(z0, z1, off, csr, inv);
    k_agg<<<N_NODES / 4, 256, 0, stream>>>(z1, z0, off, csr, inv);

    // final: bias + relu -> out, attention head -> att
    k_final<<<(N_NODES + 31) / 32, 128, 0, stream>>>(z0, b2, wa1b, ba1, Wa2, ba2, out_mat, att);
}

// Round 8
// 194.190 us; speedup vs baseline: 1.1741x; 1.0373x over previous
//
#include <hip/hip_runtime.h>
#include <hip/hip_bf16.h>
#include <math.h>

#define N_NODES 10000
#define NP      10016   // padded row count for z buffers (32-row tiles, no store guards)
#define E_EDGES 320000
#define F_IN    384
#define H1      256
#define H2      128
#define ATT1    64

typedef __attribute__((ext_vector_type(8))) short bf16x8;
typedef __attribute__((ext_vector_type(4))) float f32x4;

static __device__ inline unsigned short f2bf(float f) {
    unsigned u = __float_as_uint(f);
    unsigned r = (u + 0x7fffu + ((u >> 16) & 1u)) >> 16;   // RNE
    return (unsigned short)r;
}

static __device__ inline unsigned pk2bf(float a, float b) {
    __hip_bfloat162 h2 = __float22bfloat162_rn(make_float2(a, b));
    return *reinterpret_cast<unsigned*>(&h2);   // v_cvt_pk_bf16_f32
}

static __device__ inline float bflo(unsigned v) { return __uint_as_float(v << 16); }
static __device__ inline float bfhi(unsigned v) { return __uint_as_float(v & 0xffff0000u); }
static __device__ inline float bf2f(short s) {
    return __uint_as_float(((unsigned)(unsigned short)s) << 16);
}

// ---------- fused: weight fp32->bf16 converts + degree count
__global__ void k_convdeg(const float* __restrict__ W1, const float* __restrict__ W2,
                          const float* __restrict__ Wa1,
                          unsigned short* __restrict__ w1b, unsigned short* __restrict__ w2b,
                          unsigned short* __restrict__ wa1b,
                          const int* __restrict__ tgt, int* __restrict__ deg) {
    const int n1 = H1 * F_IN / 4;   // 24576
    const int n2 = H2 * H1 / 4;     // 8192
    const int n3 = ATT1 * H2 / 4;   // 2048
    const int nc = n1 + n2 + n3;    // 34816
    int i = blockIdx.x * blockDim.x + threadIdx.x;
    if (i < nc) {
        const float4* src;
        ushort4* dst;
        int j;
        if (i < n1)           { src = (const float4*)W1;  dst = (ushort4*)w1b;  j = i; }
        else if (i < n1 + n2) { src = (const float4*)W2;  dst = (ushort4*)w2b;  j = i - n1; }
        else                  { src = (const float4*)Wa1; dst = (ushort4*)wa1b; j = i - n1 - n2; }
        float4 v = src[j];
        ushort4 o;
        o.x = f2bf(v.x); o.y = f2bf(v.y); o.z = f2bf(v.z); o.w = f2bf(v.w);
        dst[j] = o;
    } else {
        int e = i - nc;
        if (e < E_EDGES) atomicAdd(&deg[tgt[e]], 1);
    }
}

// ---------- exclusive scan over deg (single block, 1024 threads)
__global__ __launch_bounds__(1024) void k_scan(const int* __restrict__ deg, int* __restrict__ off,
                                               int* __restrict__ cursor, float* __restrict__ inv) {
    const int CH = 10;
    int tid = threadIdx.x;
    int base = tid * CH;
    int sum = 0;
    int local[CH];
    #pragma unroll
    for (int i = 0; i < CH; i++) {
        int idx = base + i;
        int v = (idx < N_NODES) ? deg[idx] : 0;
        local[i] = sum;
        sum += v;
    }
    __shared__ int sd[1024];
    sd[tid] = sum;
    __syncthreads();
    for (int d = 1; d < 1024; d <<= 1) {
        int v = (tid >= d) ? sd[tid - d] : 0;
        __syncthreads();
        sd[tid] += v;
        __syncthreads();
    }
    int excl = sd[tid] - sum;
    #pragma unroll
    for (int i = 0; i < CH; i++) {
        int idx = base + i;
        if (idx < N_NODES) {
            int o = local[i] + excl;
            off[idx] = o;
            cursor[idx] = o;
            inv[idx] = 1.0f / (float)(deg[idx] + 1);
        }
    }
    if (tid == 1023) off[N_NODES] = sd[1023];
}

// ---------- fused: fc1+proj GEMM (blocks 0..NBLK_FC-1) + CSR bin fill (remaining blocks)
// fc12: z = relu(x @ W1^T + b1) @ W2^T   (N x 128, bf16, NO bias/relu on z)
#define NBLK_FC  ((N_NODES + 31) / 32)          // 313
#define NBLK_FIL ((E_EDGES + 255) / 256)        // 1250
#define S1 264   // LDS row stride (ushorts) for the 32x256 h tile
__global__ __launch_bounds__(256) void k_fc12fill(const float* __restrict__ x,
                                                  const unsigned short* __restrict__ w1b,
                                                  const float* __restrict__ b1,
                                                  const unsigned short* __restrict__ w2b,
                                                  unsigned short* __restrict__ z,
                                                  const int* __restrict__ srcv,
                                                  const int* __restrict__ tgt,
                                                  int* __restrict__ cursor,
                                                  int* __restrict__ csr) {
    __shared__ unsigned short sh[32 * S1];
    if (blockIdx.x >= NBLK_FC) {
        // ----- CSR fill path
        int e = (blockIdx.x - NBLK_FC) * 256 + threadIdx.x;
        if (e < E_EDGES) {
            int t = tgt[e];
            int p = atomicAdd(&cursor[t], 1);
            csr[p] = srcv[e];
        }
        return;
    }
    // ----- fc12 path
    int wave = threadIdx.x >> 6;
    int lane = threadIdx.x & 63;
    int m0 = blockIdx.x * 32;
    int ml = lane & 15, quad = lane >> 4;
    {   // stage 1: h = relu(x @ W1^T + b1), inline fp32->bf16 convert of x
        int nbase = wave * 64;
        int ra0 = m0 + ml;
        int ra1 = m0 + 16 + ml; if (ra1 > N_NODES - 1) ra1 = N_NODES - 1;
        const float* Ar0 = x + (size_t)ra0 * F_IN + quad * 8;
        const float* Ar1 = x + (size_t)ra1 * F_IN + quad * 8;
        const bf16x8* Brow[4];
        #pragma unroll
        for (int j = 0; j < 4; j++)
            Brow[j] = (const bf16x8*)(w1b + (size_t)(nbase + j * 16 + ml) * F_IN + quad * 8);
        f32x4 acc0[4] = {{0,0,0,0},{0,0,0,0},{0,0,0,0},{0,0,0,0}};
        f32x4 acc1[4] = {{0,0,0,0},{0,0,0,0},{0,0,0,0},{0,0,0,0}};
        for (int kk = 0; kk < F_IN / 32; kk++) {
            float4 f0 = *(const float4*)(Ar0 + kk * 32);
            float4 f1 = *(const float4*)(Ar0 + kk * 32 + 4);
            float4 g0 = *(const float4*)(Ar1 + kk * 32);
            float4 g1 = *(const float4*)(Ar1 + kk * 32 + 4);
            bf16x8 a0, a1;
            ((unsigned*)&a0)[0] = pk2bf(f0.x, f0.y);
            ((unsigned*)&a0)[1] = pk2bf(f0.z, f0.w);
            ((unsigned*)&a0)[2] = pk2bf(f1.x, f1.y);
            ((unsigned*)&a0)[3] = pk2bf(f1.z, f1.w);
            ((unsigned*)&a1)[0] = pk2bf(g0.x, g0.y);
            ((unsigned*)&a1)[1] = pk2bf(g0.z, g0.w);
            ((unsigned*)&a1)[2] = pk2bf(g1.x, g1.y);
            ((unsigned*)&a1)[3] = pk2bf(g1.z, g1.w);
            #pragma unroll
            for (int j = 0; j < 4; j++) {
                bf16x8 b = Brow[j][kk * 4];
                acc0[j] = __builtin_amdgcn_mfma_f32_16x16x32_bf16(a0, b, acc0[j], 0, 0, 0);
                acc1[j] = __builtin_amdgcn_mfma_f32_16x16x32_bf16(a1, b, acc1[j], 0, 0, 0);
            }
        }
        #pragma unroll
        for (int j = 0; j < 4; j++) {
            int col = nbase + j * 16 + ml;
            float bb = b1[col];
            #pragma unroll
            for (int r = 0; r < 4; r++) {
                int lr = quad * 4 + r;
                float v0 = acc0[j][r] + bb;
                sh[lr * S1 + col] = f2bf(v0 > 0.f ? v0 : 0.f);
                float v1 = acc1[j][r] + bb;
                sh[(lr + 16) * S1 + col] = f2bf(v1 > 0.f ? v1 : 0.f);
            }
        }
    }
    __syncthreads();
    {   // stage 2: z = h @ W2^T, wave w -> cols [w*32, w*32+32), A from LDS
        int c0 = wave * 32;
        const unsigned short* pA0 = sh + ml * S1 + quad * 8;
        const unsigned short* pA1 = sh + (16 + ml) * S1 + quad * 8;
        const bf16x8* B0 = (const bf16x8*)(w2b + (size_t)(c0 + ml) * H1 + quad * 8);
        const bf16x8* B1 = (const bf16x8*)(w2b + (size_t)(c0 + 16 + ml) * H1 + quad * 8);
        f32x4 za[2][2] = {{{0,0,0,0},{0,0,0,0}},{{0,0,0,0},{0,0,0,0}}};
        #pragma unroll
        for (int kk = 0; kk < H1 / 32; kk++) {
            bf16x8 a0 = *(const bf16x8*)(pA0 + kk * 32);
            bf16x8 a1 = *(const bf16x8*)(pA1 + kk * 32);
            bf16x8 b0 = B0[kk * 4];
            bf16x8 b1 = B1[kk * 4];
            za[0][0] = __builtin_amdgcn_mfma_f32_16x16x32_bf16(a0, b0, za[0][0], 0, 0, 0);
            za[1][0] = __builtin_amdgcn_mfma_f32_16x16x32_bf16(a1, b0, za[1][0], 0, 0, 0);
            za[0][1] = __builtin_amdgcn_mfma_f32_16x16x32_bf16(a0, b1, za[0][1], 0, 0, 0);
            za[1][1] = __builtin_amdgcn_mfma_f32_16x16x32_bf16(a1, b1, za[1][1], 0, 0, 0);
        }
        #pragma unroll
        for (int j2 = 0; j2 < 2; j2++) {
            int col = c0 + j2 * 16 + ml;
            #pragma unroll
            for (int r = 0; r < 4; r++) {
                int row0 = m0 + quad * 4 + r;          // z padded to NP rows: no guard
                z[(size_t)row0 * H2 + col] = f2bf(za[0][j2][r]);
                z[(size_t)(row0 + 16) * H2 + col] = f2bf(za[1][j2][r]);
            }
        }
    }
}

// ---------- agg pass 1: zout[t] = 0.7*zin[t] + 0.3*inv[t]*sum zin[nbr]
// 4 nodes per 256-thread block; csr bulk-loaded per 64-chunk, readlane -> SGPR gather base
__global__ __launch_bounds__(256) void k_agg1(const unsigned short* __restrict__ zin,
                                              unsigned short* __restrict__ zout,
                                              const int* __restrict__ off,
                                              const int* __restrict__ csr,
                                              const float* __restrict__ inv) {
    int t = blockIdx.x * 4 + (threadIdx.x >> 6);
    int tid = threadIdx.x & 63;
    int s0 = off[t], s1 = off[t + 1];
    const unsigned* base = (const unsigned*)zin;   // row stride 64 uints
    float a0 = 0.f, a1 = 0.f;
    for (int e0 = s0; e0 < s1; e0 += 64) {
        int cnt = s1 - e0; if (cnt > 64) cnt = 64;
        int c = (e0 + tid < s1) ? csr[e0 + tid] : 0;
        int j = 0;
        for (; j + 4 <= cnt; j += 4) {
            int sA = __builtin_amdgcn_readlane(c, j);
            int sB = __builtin_amdgcn_readlane(c, j + 1);
            int sC = __builtin_amdgcn_readlane(c, j + 2);
            int sD = __builtin_amdgcn_readlane(c, j + 3);
            unsigned vA = base[(size_t)sA * 64 + tid];
            unsigned vB = base[(size_t)sB * 64 + tid];
            unsigned vC = base[(size_t)sC * 64 + tid];
            unsigned vD = base[(size_t)sD * 64 + tid];
            a0 += bflo(vA); a1 += bfhi(vA);
            a0 += bflo(vB); a1 += bfhi(vB);
            a0 += bflo(vC); a1 += bfhi(vC);
            a0 += bflo(vD); a1 += bfhi(vD);
        }
        for (; j < cnt; j++) {
            int s = __builtin_amdgcn_readlane(c, j);
            unsigned v = base[(size_t)s * 64 + tid];
            a0 += bflo(v); a1 += bfhi(v);
        }
    }
    unsigned sv = base[(size_t)t * 64 + tid];
    float iv = 0.3f * inv[t];
    float r0 = 0.7f * bflo(sv) + iv * a0;
    float r1 = 0.7f * bfhi(sv) + iv * a1;
    // NOT nontemporal: this is pass 2's gather table, keep it in L2
    ((unsigned*)zout)[(size_t)t * 64 + tid] = pk2bf(r0, r1);
}

// ---------- agg pass 2 + epilogue: out = relu(agg(z) + b2) -> d_out;
// att = sigmoid(relu(out @ Wa1^T + ba1) @ Wa2^T + ba2) per node (wave-local, LDS row)
__global__ __launch_bounds__(256) void k_agg2fin(const unsigned short* __restrict__ zin,
                                                 const int* __restrict__ off,
                                                 const int* __restrict__ csr,
                                                 const float* __restrict__ inv,
                                                 const float* __restrict__ b2,
                                                 const unsigned short* __restrict__ wa1b,
                                                 const float* __restrict__ ba1,
                                                 const float* __restrict__ Wa2,
                                                 const float* __restrict__ ba2,
                                                 float* __restrict__ out,
                                                 float* __restrict__ att) {
    __shared__ float sout[4][128];
    int nl = threadIdx.x >> 6;
    int t = blockIdx.x * 4 + nl;
    int tid = threadIdx.x & 63;
    int s0 = off[t], s1 = off[t + 1];
    const unsigned* base = (const unsigned*)zin;
    float a0 = 0.f, a1 = 0.f;
    for (int e0 = s0; e0 < s1; e0 += 64) {
        int cnt = s1 - e0; if (cnt > 64) cnt = 64;
        int c = (e0 + tid < s1) ? csr[e0 + tid] : 0;
        int j = 0;
        for (; j + 4 <= cnt; j += 4) {
            int sA = __builtin_amdgcn_readlane(c, j);
            int sB = __builtin_amdgcn_readlane(c, j + 1);
            int sC = __builtin_amdgcn_readlane(c, j + 2);
            int sD = __builtin_amdgcn_readlane(c, j + 3);
            unsigned vA = base[(size_t)sA * 64 + tid];
            unsigned vB = base[(size_t)sB * 64 + tid];
            unsigned vC = base[(size_t)sC * 64 + tid];
            unsigned vD = base[(size_t)sD * 64 + tid];
            a0 += bflo(vA); a1 += bfhi(vA);
            a0 += bflo(vB); a1 += bfhi(vB);
            a0 += bflo(vC); a1 += bfhi(vC);
            a0 += bflo(vD); a1 += bfhi(vD);
        }
        for (; j < cnt; j++) {
            int s = __builtin_amdgcn_readlane(c, j);
            unsigned v = base[(size_t)s * 64 + tid];
            a0 += bflo(v); a1 += bfhi(v);
        }
    }
    unsigned sv = base[(size_t)t * 64 + tid];
    float iv = 0.3f * inv[t];
    float2 bb = *(const float2*)(b2 + 2 * tid);
    float f0 = 0.7f * bflo(sv) + iv * a0 + bb.x;  f0 = f0 > 0.f ? f0 : 0.f;
    float f1 = 0.7f * bfhi(sv) + iv * a1 + bb.y;  f1 = f1 > 0.f ? f1 : 0.f;
    *(float2*)(out + (size_t)t * H2 + 2 * tid) = make_float2(f0, f1);
    // stage row for the att head (wave-local; no __syncthreads needed)
    *(float2*)(&sout[nl][2 * tid]) = make_float2(f0, f1);
    // att: lane tid computes hidden unit tid: dot(out_row, Wa1[tid]) over K=128
    float acc = ba1[tid];
    const bf16x8* wrow = (const bf16x8*)(wa1b + (size_t)tid * H2);
    const float* srow = sout[nl];
    #pragma unroll
    for (int k8 = 0; k8 < 16; k8++) {
        bf16x8 w = wrow[k8];
        #pragma unroll
        for (int u = 0; u < 8; u++)
            acc += bf2f(w[u]) * srow[k8 * 8 + u];
    }
    float g = (acc > 0.f ? acc : 0.f) * Wa2[tid];
    #pragma unroll
    for (int d = 1; d < 64; d <<= 1) g += __shfl_xor(g, d, 64);
    if (tid == 0) att[t] = 1.f / (1.f + expf(-g));
}

extern "C" void kernel_launch(void* const* d_in, const int* in_sizes, int n_in,
                              void* d_out, int out_size, void* d_ws, size_t ws_size,
                              hipStream_t stream) {
    const float* x   = (const float*)d_in[0];
    const int*   ei  = (const int*)d_in[1];
    const float* W1  = (const float*)d_in[2];
    const float* b1  = (const float*)d_in[3];
    const float* W2  = (const float*)d_in[4];
    const float* b2  = (const float*)d_in[5];
    const float* Wa1 = (const float*)d_in[6];
    const float* ba1 = (const float*)d_in[7];
    const float* Wa2 = (const float*)d_in[8];
    const float* ba2 = (const float*)d_in[9];
    const int* srcv = ei;
    const int* tgt  = ei + E_EDGES;

    float* out_mat = (float*)d_out;                 // N x 128
    float* att     = out_mat + N_NODES * H2;        // N x 1

    // workspace layout
    unsigned short* w1b  = (unsigned short*)d_ws;                // H1*F_IN
    unsigned short* w2b  = w1b + (size_t)H1 * F_IN;              // H2*H1
    unsigned short* wa1b = w2b + (size_t)H2 * H1;                // ATT1*H2
    unsigned short* z0   = wa1b + (size_t)ATT1 * H2;             // NP*128
    unsigned short* z1   = z0 + (size_t)NP * H2;                 // NP*128
    float* inv  = (float*)(z1 + (size_t)NP * H2);                // N
    int* deg    = (int*)(inv + N_NODES);                         // N
    int* off    = deg + N_NODES;                                 // N+1
    int* cursor = off + N_NODES + 1;                             // N
    int* csr    = cursor + N_NODES;                              // E

    (void)hipMemsetAsync(deg, 0, N_NODES * sizeof(int), stream);

    // weight converts + degree count (fused)
    {
        const int nc = (H1 * F_IN + H2 * H1 + ATT1 * H2) / 4;  // 34816
        int total = nc + E_EDGES;
        k_convdeg<<<(total + 255) / 256, 256, 0, stream>>>(W1, W2, Wa1, w1b, w2b, wa1b, tgt, deg);
    }

    k_scan<<<1, 1024, 0, stream>>>(deg, off, cursor, inv);

    // fused fc1+proj GEMM (313 blocks) + CSR fill (1250 blocks)
    k_fc12fill<<<NBLK_FC + NBLK_FIL, 256, 0, stream>>>(x, w1b, b1, w2b, z0,
                                                       srcv, tgt, cursor, csr);

    // agg pass 1 (z0 -> z1)
    k_agg1<<<N_NODES / 4, 256, 0, stream>>>(z0, z1, off, csr, inv);

    // agg pass 2 + bias/relu -> out, att head -> att
    k_agg2fin<<<N_NODES / 4, 256, 0, stream>>>(z1, off, csr, inv, b2,
                                               wa1b, ba1, Wa2, ba2, out_mat, att);
}